// Round 3
// baseline (235.092 us; speedup 1.0000x reference)
//
#include <hip/hip_runtime.h>
#include <stdint.h>

// WeightsDropout: per row of 4096 f32 (uniform in (1e-4,1)), drop the 2048
// smallest (stable tie-break: smaller index dropped first), softmax survivors.
//
// R6: BLOCK=512, 2 rows/block, 8 elems/thread/row (same 16 data regs as R5b
// -> stays in the 64-VGPR class; __launch_bounds__(512,8) = 4 blocks x 8
// waves = 32 waves/CU). Barrier tax halved per row; 2x loads in flight per
// block; the two 256-bucket scans run in parallel on waves 0/1.
// Max subtraction removed entirely: inputs < 1 so exp(x) <= e, and
// exp(x)/sum == exp(x-m)/sum(exp(x-m)) exactly; saves a reduce + a pass.
// Band-count merged into the histogram pass (chi = clo + scan total).
// Output stored non-temporal (never re-read; preserves input L3 residency).
// Selection: uniform values -> k-th order statistic in [0.45,0.55) whp;
// fine 256-bucket histogram over that band (~410 elems/row), exact
// lex-(bits,idx) rank inside the crossing bucket. Block-uniform exact
// bisection fallback guarantees correctness for any input.
constexpr int N     = 4096;
constexpr int KSEL  = 2048;          // int(N * 0.5)
constexpr int BLOCK = 512;
constexpr int NW    = BLOCK / 64;    // 8 waves
constexpr int RPB   = 2;             // rows per block
constexpr int EPT   = N / BLOCK;     // 8 elements/thread/row
constexpr int NB    = 256;           // fine buckets over the band
constexpr int CAP   = 64;            // candidate capacity (E[#]=1.6)
constexpr float P1  = 0.45f;
constexpr float P2  = 0.55f;
constexpr float BSCALE = 2560.0f;    // NB / (P2 - P1)

typedef float vfloat4 __attribute__((ext_vector_type(4)));

__global__ __launch_bounds__(BLOCK, 8)
void wdrop_kernel(const float* __restrict__ w, float* __restrict__ out) {
    const int t = threadIdx.x, wid = t >> 6, lane = t & 63;
    const uint64_t row0 = (uint64_t)blockIdx.x * RPB;

    __shared__ alignas(16) int hist[RPB][NB];
    __shared__ int      redpk[NW];           // packed clo reduce; reused by fallback
    __shared__ float    redf[RPB][NW];
    __shared__ int      selb[RPB], jms[RPB], cn[RPB];
    __shared__ uint32_t cb[RPB][CAP];
    __shared__ int      ci[RPB][CAP];
    __shared__ uint32_t thrT[RPB], thrI[RPB];

    // ---- issue all 4 float4 loads up front, zero LDS while in flight
    uint32_t v[RPB][EPT];
    {
        const uint4* wf0 = (const uint4*)(w + row0 * N);
        const uint4* wf1 = (const uint4*)(w + (row0 + 1) * N);
        uint4 u0[EPT / 4], u1[EPT / 4];
#pragma unroll
        for (int j = 0; j < EPT / 4; ++j) u0[j] = wf0[j * BLOCK + t];
#pragma unroll
        for (int j = 0; j < EPT / 4; ++j) u1[j] = wf1[j * BLOCK + t];
#pragma unroll
        for (int j = 0; j < EPT / 4; ++j) {
            v[0][j*4+0]=u0[j].x; v[0][j*4+1]=u0[j].y; v[0][j*4+2]=u0[j].z; v[0][j*4+3]=u0[j].w;
            v[1][j*4+0]=u1[j].x; v[1][j*4+1]=u1[j].y; v[1][j*4+2]=u1[j].z; v[1][j*4+3]=u1[j].w;
        }
    }
    ((int*)hist)[t] = 0;                     // t < 512 == RPB*NB
    if (t < RPB) { selb[t] = -1; cn[t] = 0; }
    __syncthreads();                                          // B1 (zero visible)

    // ---- one pass: count below-band + fine histogram of the band
    int clo0 = 0, clo1 = 0;
#pragma unroll
    for (int e = 0; e < EPT; ++e) {
        const float f0 = __uint_as_float(v[0][e]);
        const float f1 = __uint_as_float(v[1][e]);
        clo0 += (f0 < P1); clo1 += (f1 < P1);
        if (f0 >= P1 && f0 < P2)
            atomicAdd(&hist[0][min((int)((f0 - P1) * BSCALE), NB - 1)], 1);
        if (f1 >= P1 && f1 < P2)
            atomicAdd(&hist[1][min((int)((f1 - P1) * BSCALE), NB - 1)], 1);
    }
    int pk = (clo0 << 16) | clo1;            // fields stay < 4096: no carry
#pragma unroll
    for (int off = 32; off > 0; off >>= 1) pk += __shfl_xor(pk, off, 64);
    if (lane == 0) redpk[wid] = pk;
    __syncthreads();                                          // B2 (hist + clo)

    // ---- parallel scans: wave r scans row r's 256 buckets, finds crossing
    if (wid < RPB) {
        const int r = wid;
        const int4 hh = ((const int4*)hist[r])[lane];        // 4 buckets/lane
        const int a0 = hh.x, a1 = a0 + hh.y, a2 = a1 + hh.z, a3 = a2 + hh.w;
        int sc = a3;
#pragma unroll
        for (int off = 1; off < 64; off <<= 1) {
            const int u = __shfl_up(sc, off, 64);
            if (lane >= off) sc += u;
        }
        const int base = sc - a3;            // exclusive prefix of this lane's 4
        int cloB = 0;
#pragma unroll
        for (int i = 0; i < NW; ++i) {
            const int p = redpk[i];
            cloB += (r == 0) ? (p >> 16) : (p & 0xFFFF);
        }
        const int tot = __shfl(sc, 63, 64);  // total band count
        const int chiB = cloB + tot;
        if (cloB < KSEL && chiB >= KSEL) {   // k-th value in [P1,P2)
            const int jrank = KSEL - cloB;   // 1-indexed rank within band
            const int inc[4] = {base + a0, base + a1, base + a2, base + a3};
            const int exc[4] = {base, base + a0, base + a1, base + a2};
#pragma unroll
            for (int i = 0; i < 4; ++i)
                if (exc[i] < jrank && jrank <= inc[i]) {
                    selb[r] = lane * 4 + i;
                    jms[r]  = jrank - exc[i] - 1;   // 0-indexed rank in bucket
                }
        }
    }
    __syncthreads();                                          // B3 (selb/jms)

    // ---- gather candidates in crossing bucket
#pragma unroll
    for (int r = 0; r < RPB; ++r) {
        const int bs = selb[r];
        if (bs >= 0) {
#pragma unroll
            for (int e = 0; e < EPT; ++e) {
                const float f = __uint_as_float(v[r][e]);
                if (f >= P1 && f < P2 && min((int)((f - P1) * BSCALE), NB - 1) == bs) {
                    const int slot = atomicAdd(&cn[r], 1);
                    if (slot < CAP) {
                        cb[r][slot] = v[r][e];
                        ci[r][slot] = ((e >> 2) * BLOCK + t) * 4 + (e & 3);
                    }
                }
            }
        }
    }
    __syncthreads();                                          // B4 (candidates)

    // ---- exact lex rank among candidates -> (T, thrIdx) = k-th smallest pair
    const int cn0 = cn[0], cn1 = cn[1];
    const bool ok0 = (selb[0] >= 0) && (cn0 <= CAP);
    const bool ok1 = (selb[1] >= 0) && (cn1 <= CAP);
    if (ok0 && t < cn0) {
        const uint32_t myb = cb[0][t]; const int myi = ci[0][t];
        int rank = 0;
        for (int q = 0; q < cn0; ++q)
            rank += (cb[0][q] < myb) || (cb[0][q] == myb && ci[0][q] < myi);
        if (rank == jms[0]) { thrT[0] = myb; thrI[0] = (uint32_t)myi; }
    }
    if (ok1 && t >= 256 && (t - 256) < cn1) {
        const int t2 = t - 256;
        const uint32_t myb = cb[1][t2]; const int myi = ci[1][t2];
        int rank = 0;
        for (int q = 0; q < cn1; ++q)
            rank += (cb[1][q] < myb) || (cb[1][q] == myb && ci[1][q] < myi);
        if (rank == jms[1]) { thrT[1] = myb; thrI[1] = (uint32_t)myi; }
    }

    // ---- exact fallback (block-uniform; never taken for uniform data)
#pragma unroll
    for (int r = 0; r < RPB; ++r) {
        const bool ok = (r == 0) ? ok0 : ok1;
        if (!ok) {
            uint32_t blo = 0u, bhi = 0x7f7fffffu;
            while (blo < bhi) {
                const uint32_t mid = blo + ((bhi - blo) >> 1);
                int c = 0;
#pragma unroll
                for (int e = 0; e < EPT; ++e) c += __popcll(__ballot(v[r][e] <= mid));
                __syncthreads();
                if (lane == 0) redpk[wid] = c;
                __syncthreads();
                int tot = 0;
#pragma unroll
                for (int i = 0; i < NW; ++i) tot += redpk[i];
                if (tot >= KSEL) bhi = mid; else blo = mid + 1;
            }
            const uint32_t T = blo;
            int c = 0;
#pragma unroll
            for (int e = 0; e < EPT; ++e) c += __popcll(__ballot(v[r][e] < T));
            __syncthreads();
            if (lane == 0) redpk[wid] = c;
            __syncthreads();
            int clt = 0;
#pragma unroll
            for (int i = 0; i < NW; ++i) clt += redpk[i];
            const int need = KSEL - clt;
            int ilo = 0, ihi = N - 1;
            while (ilo < ihi) {
                const int imid = (ilo + ihi) >> 1;
                int cc = 0;
#pragma unroll
                for (int e = 0; e < EPT; ++e) {
                    const int idx = ((e >> 2) * BLOCK + t) * 4 + (e & 3);
                    cc += __popcll(__ballot(v[r][e] == T && idx <= imid));
                }
                __syncthreads();
                if (lane == 0) redpk[wid] = cc;
                __syncthreads();
                int tot = 0;
#pragma unroll
                for (int i = 0; i < NW; ++i) tot += redpk[i];
                if (tot >= need) ihi = imid; else ilo = imid + 1;
            }
            if (t == 0) { thrT[r] = T; thrI[r] = (uint32_t)ilo; }
        }
    }
    __syncthreads();                                          // B5 (threshold)

    // ---- keep + exp (no max: inputs < 1, exp(x) <= e) + per-row block sums
    const uint32_t T0 = thrT[0]; const int ti0 = (int)thrI[0];
    const uint32_t T1 = thrT[1]; const int ti1 = (int)thrI[1];
    float acc0 = 0.0f, acc1 = 0.0f;
#pragma unroll
    for (int e = 0; e < EPT; ++e) {
        const int idx = ((e >> 2) * BLOCK + t) * 4 + (e & 3);
        const bool k0 = (v[0][e] > T0) || (v[0][e] == T0 && idx > ti0);
        const bool k1 = (v[1][e] > T1) || (v[1][e] == T1 && idx > ti1);
        const float e0 = k0 ? __expf(__uint_as_float(v[0][e])) : 0.0f;
        const float e1 = k1 ? __expf(__uint_as_float(v[1][e])) : 0.0f;
        v[0][e] = __float_as_uint(e0); acc0 += e0;
        v[1][e] = __float_as_uint(e1); acc1 += e1;
    }
#pragma unroll
    for (int off = 32; off > 0; off >>= 1) {
        acc0 += __shfl_xor(acc0, off, 64);
        acc1 += __shfl_xor(acc1, off, 64);
    }
    if (lane == 0) { redf[0][wid] = acc0; redf[1][wid] = acc1; }
    __syncthreads();                                          // B6 (sums)
    float s0 = redf[0][0], s1 = redf[1][0];
#pragma unroll
    for (int i = 1; i < NW; ++i) { s0 += redf[0][i]; s1 += redf[1][i]; }
    const float inv0 = 1.0f / s0, inv1 = 1.0f / s1;

    vfloat4* of0 = (vfloat4*)(out + row0 * N);
    vfloat4* of1 = (vfloat4*)(out + (row0 + 1) * N);
#pragma unroll
    for (int j = 0; j < EPT / 4; ++j) {
        vfloat4 o0, o1;
        o0.x = __uint_as_float(v[0][j*4+0]) * inv0;
        o0.y = __uint_as_float(v[0][j*4+1]) * inv0;
        o0.z = __uint_as_float(v[0][j*4+2]) * inv0;
        o0.w = __uint_as_float(v[0][j*4+3]) * inv0;
        o1.x = __uint_as_float(v[1][j*4+0]) * inv1;
        o1.y = __uint_as_float(v[1][j*4+1]) * inv1;
        o1.z = __uint_as_float(v[1][j*4+2]) * inv1;
        o1.w = __uint_as_float(v[1][j*4+3]) * inv1;
        __builtin_nontemporal_store(o0, &of0[j * BLOCK + t]);
        __builtin_nontemporal_store(o1, &of1[j * BLOCK + t]);
    }
}

extern "C" void kernel_launch(void* const* d_in, const int* in_sizes, int n_in,
                              void* d_out, int out_size, void* d_ws, size_t ws_size,
                              hipStream_t stream) {
    const float* w = (const float*)d_in[0];
    float* out = (float*)d_out;
    const int rows = in_sizes[0] / N;            // 8192
    wdrop_kernel<<<rows / RPB, BLOCK, 0, stream>>>(w, out);
}